// Round 3
// baseline (554.864 us; speedup 1.0000x reference)
//
#include <hip/hip_runtime.h>
#include <cstdint>
#include <cstddef>

#define B_   32
#define TIN  512
#define D_   384
#define F_   384
#define TOUT 4096
#define TPAD 514            // 512 + zero row on each side
#define MTOT (B_ * TIN)     // 16384

typedef __bf16 bf16x8 __attribute__((ext_vector_type(8)));
typedef float  f32x4  __attribute__((ext_vector_type(4)));

__device__ __forceinline__ unsigned short f2bf(float f) {
  unsigned int u = __float_as_uint(f);
  u += 0x7fff + ((u >> 16) & 1);   // round-to-nearest-even
  return (unsigned short)(u >> 16);
}

__device__ __forceinline__ void load16_to_lds(const void* g, void* l) {
  __builtin_amdgcn_global_load_lds(
      (const __attribute__((address_space(1))) unsigned int*)g,
      (__attribute__((address_space(3))) unsigned int*)l, 16, 0, 0);
}

// ---------------------------------------------------------------- prep (fused)
#define PB_CUM 32
#define PB_W   3456
#define PB_Z   96
#define PB_PX  6168
#define PB_TOT (PB_CUM + PB_W + PB_Z + PB_PX)

__global__ __launch_bounds__(256) void prep_all(
    const float* __restrict__ w1, const float* __restrict__ w2,
    unsigned short* __restrict__ Wt1, unsigned short* __restrict__ Wt2,
    unsigned short* __restrict__ h1p,
    const int* __restrict__ target, int* __restrict__ idxv,
    const float4* __restrict__ x4, unsigned short* __restrict__ xp) {
  int bx = blockIdx.x;
  int tid = threadIdx.x;

  if (bx < PB_CUM) {
    // ---- cumsum + binary search (one block per batch, 256 thr handle 512)
    __shared__ int ends[512];
    __shared__ int ps[256];
    int b = bx;
    int a0 = target[b * TIN + 2 * tid];
    int a1 = target[b * TIN + 2 * tid + 1];
    ps[tid] = a0 + a1;
    __syncthreads();
    for (int off = 1; off < 256; off <<= 1) {
      int add = (tid >= off) ? ps[tid - off] : 0;
      __syncthreads();
      ps[tid] += add;
      __syncthreads();
    }
    int incl = ps[tid];
    ends[2 * tid + 1] = incl;
    ends[2 * tid]     = incl - a1;
    __syncthreads();
    for (int p = 0; p < 16; ++p) {
      int m = p * 256 + tid;
      int lo = 0, hi = 512;              // first j with ends[j] > m
      while (lo < hi) {
        int mid = (lo + hi) >> 1;
        if (ends[mid] <= m) lo = mid + 1; else hi = mid;
      }
      idxv[b * TOUT + m] = (lo < TIN) ? lo : -1;
    }
    return;
  }
  bx -= PB_CUM;

  if (bx < PB_W) {
    int g = bx * 256 + tid;                     // < 884736
    const int WE = 3 * F_ * D_;                 // 442368
    int which = g >= WE;
    const float* w = which ? w2 : w1;
    unsigned short* o = which ? Wt2 : Wt1;
    int e = g - which * WE;
    int k = e / (F_ * D_);
    int rem = e - k * (F_ * D_);
    int f = rem / D_;
    int d = rem - f * D_;
    o[e] = f2bf(w[(f * D_ + d) * 3 + k]);
    return;
  }
  bx -= PB_W;

  if (bx < PB_Z) {
    int z = bx * 256 + tid;                     // < 24576
    int zr = z / D_;
    int c = z - zr * D_;
    int b = zr >> 1;
    int tp = (zr & 1) ? (TPAD - 1) : 0;
    h1p[((size_t)(b * TPAD + tp)) * D_ + c] = 0;
    return;
  }
  bx -= PB_Z;

  {
    int g = bx * 256 + tid;                     // 32*514*96 = 1,579,008
    int row = g / 96;
    int c4 = g - row * 96;
    int b = row / TPAD;
    int tp = row - b * TPAD;
    ushort4 o;
    if (tp == 0 || tp == TPAD - 1) {
      o.x = 0; o.y = 0; o.z = 0; o.w = 0;
    } else {
      float4 v = x4[((size_t)(b * TIN + tp - 1)) * 96 + c4];
      o.x = f2bf(v.x); o.y = f2bf(v.y); o.z = f2bf(v.z); o.w = f2bf(v.w);
    }
    *(ushort4*)(xp + (size_t)row * D_ + c4 * 4) = o;
  }
}

// ---------------------------------------------------------------- conv+LN+gather
// Grid = 640 blocks x 512 thr. bx%5==0 -> conv tile (128 of them: rows
// m0..m0+127, ALL 384 cols, K=1152); else -> gather slice (512 per launch).
// Conv tile: 8 waves in a 2x4 grid, each 64x96 = 4x6 mfma_f32_16x16x32_bf16.
// Epilogue: 32-row groups staged to LDS (48 KB, aliases K-staging tiles),
// LayerNorm per row, then MODE 0: relu->bf16 h1p; MODE 1: dot(lin_w)->dur.
template <int MODE>
__global__ __launch_bounds__(512, 2) void conv_fused(
    const unsigned short* __restrict__ Ap, const unsigned short* __restrict__ Wt,
    const float* __restrict__ bias,
    const float* __restrict__ gam, const float* __restrict__ bet,
    const float* __restrict__ lw, const float* __restrict__ lb,
    unsigned short* __restrict__ hp, float* __restrict__ dur,
    const float4* __restrict__ x4, const int* __restrict__ idxv,
    float4* __restrict__ out4, int half) {
  __shared__ __align__(16) char smem[49152];
  unsigned short* As = (unsigned short*)smem;            // 8 KB  (128x32 bf16)
  unsigned short* Bs = (unsigned short*)(smem + 8192);   // 24 KB (384x32 bf16)
  float* epi = (float*)smem;                             // 48 KB (32x384 f32)

  const int bx  = blockIdx.x;
  const int tid = threadIdx.x;
  const int cbq = bx / 5;

  if (bx - cbq * 5 != 0) {
    // ---------------- gather: 512 blocks x 24 rounds x 512 float4
    int gidx = bx - cbq - 1;                    // 0..511
    size_t g = (size_t)half * 6291456 + (size_t)gidx * 512 + tid;
    for (int it = 0; it < 24; ++it, g += 262144) {
      unsigned int gu = (unsigned int)g;
      int fr = gu / 96;
      int c  = gu - fr * 96;
      int id = idxv[fr];
      int b  = fr >> 12;
      float4 v = {0.f, 0.f, 0.f, 0.f};
      if (id >= 0) v = x4[(size_t)(b * TIN + id) * 96 + c];
      out4[g] = v;
    }
    return;
  }

  // ---------------- conv tile
  const int wave = tid >> 6;        // 0..7
  const int lane = tid & 63;
  const int quad = lane >> 4;
  const int l15  = lane & 15;
  const int wr = wave >> 2;         // 0..1  -> rows wm..wm+63
  const int wc = wave & 3;          // 0..3  -> cols wn..wn+95
  const int wm = wr * 64;
  const int wn = wc * 96;
  const int m0 = cbq * 128;
  const int b  = m0 >> 9;           // tiles never cross batch (128 | 512)
  const int t0 = m0 & 511;
  const int arow = tid >> 2;        // 0..127
  const int acol = (tid & 3) * 8;   // 0,8,16,24

  f32x4 acc[4][6];
  for (int i = 0; i < 4; ++i)
    for (int j = 0; j < 6; ++j)
      acc[i][j] = (f32x4){0.f, 0.f, 0.f, 0.f};

  for (int kc = 0; kc < 36; ++kc) {
    int kw = kc / 12;
    int d0 = (kc - kw * 12) * 32;
    load16_to_lds(Ap + (size_t)(b * TPAD + t0 + arow + kw) * D_ + d0 + acol,
                  (char*)As + tid * 16);
    for (int r = 0; r < 3; ++r)
      load16_to_lds(Wt + (size_t)(kw * F_ + r * 128 + arow) * D_ + d0 + acol,
                    (char*)Bs + r * 8192 + tid * 16);
    __syncthreads();   // drains vmcnt -> tiles visible
    bf16x8 av[4], bv[6];
    for (int mi = 0; mi < 4; ++mi)
      av[mi] = *(const bf16x8*)(As + (wm + mi * 16 + l15) * 32 + quad * 8);
    for (int ni = 0; ni < 6; ++ni)
      bv[ni] = *(const bf16x8*)(Bs + (wn + ni * 16 + l15) * 32 + quad * 8);
    for (int mi = 0; mi < 4; ++mi)
      for (int ni = 0; ni < 6; ++ni)
        acc[mi][ni] = __builtin_amdgcn_mfma_f32_16x16x32_bf16(av[mi], bv[ni], acc[mi][ni], 0, 0, 0);
    __syncthreads();   // protect LDS from next staging
  }

  // hoisted per-lane column params (cols lane + j*64)
  float bse[6], gv[6], bv2[6], lwv[6];
  for (int j = 0; j < 6; ++j) {
    int c = lane + j * 64;
    gv[j]  = gam[c];
    bv2[j] = bet[c];
    if (MODE == 1) lwv[j] = lw[c];
  }
  // bias for this wave's acc columns
  float bb[6];
  for (int ni = 0; ni < 6; ++ni) bb[ni] = bias[wn + ni * 16 + l15];

  for (int g4 = 0; g4 < 4; ++g4) {            // 32-row groups
    __syncthreads();
    if (wr == (g4 >> 1)) {
      for (int mh = 0; mh < 2; ++mh) {
        int mi = (g4 & 1) * 2 + mh;
        int lrb = mh * 16 + quad * 4;         // C/D layout: row = quad*4 + reg
        for (int ni = 0; ni < 6; ++ni) {
          int c = wn + ni * 16 + l15;
          for (int r = 0; r < 4; ++r)
            epi[(lrb + r) * 384 + c] = acc[mi][ni][r] + bb[ni];
        }
      }
    }
    __syncthreads();
    for (int rr = 0; rr < 4; ++rr) {          // 32 rows / 8 waves
      int lr = wave * 4 + rr;
      int grow = m0 + g4 * 32 + lr;           // global row = b*512 + t
      const float* p = epi + lr * 384;
      float v[6], s = 0.f, ss = 0.f;
      for (int j = 0; j < 6; ++j) {
        v[j] = p[lane + j * 64];
        s += v[j];
        ss += v[j] * v[j];
      }
      for (int off = 32; off; off >>= 1) {
        s  += __shfl_xor(s, off);
        ss += __shfl_xor(ss, off);
      }
      float mean = s * (1.f / 384.f);
      float var  = ss * (1.f / 384.f) - mean * mean;
      float rstd = rsqrtf(var + 1e-5f);
      if (MODE == 0) {
        unsigned short* o = hp + ((size_t)(b * TPAD + (grow & 511) + 1)) * D_;
        for (int j = 0; j < 6; ++j) {
          float y = (v[j] - mean) * rstd * gv[j] + bv2[j];
          y = y > 0.f ? y : 0.f;
          o[lane + j * 64] = f2bf(y);
        }
      } else {
        float a = 0.f;
        for (int j = 0; j < 6; ++j) {
          float y = (v[j] - mean) * rstd * gv[j] + bv2[j];
          y = y > 0.f ? y : 0.f;
          a += y * lwv[j];
        }
        for (int off = 32; off; off >>= 1) a += __shfl_xor(a, off);
        if (lane == 0) dur[grow] = a + lb[0];
      }
    }
  }
}

// ---------------------------------------------------------------- launch
extern "C" void kernel_launch(void* const* d_in, const int* in_sizes, int n_in,
                              void* d_out, int out_size, void* d_ws, size_t ws_size,
                              hipStream_t stream) {
  const float* x      = (const float*)d_in[0];
  const int*   target = (const int*)d_in[1];
  const float* w1  = (const float*)d_in[3];
  const float* b1  = (const float*)d_in[4];
  const float* g1  = (const float*)d_in[5];
  const float* be1 = (const float*)d_in[6];
  const float* w2  = (const float*)d_in[7];
  const float* b2  = (const float*)d_in[8];
  const float* g2  = (const float*)d_in[9];
  const float* be2 = (const float*)d_in[10];
  const float* lw  = (const float*)d_in[11];
  const float* lb  = (const float*)d_in[12];

  float* out = (float*)d_out;
  float* dur = out + (size_t)B_ * TOUT * D_;   // outputs concatenated flat

  // workspace carve (all offsets 256B-aligned)
  char* ws = (char*)d_ws;
  unsigned short* xp   = (unsigned short*)(ws);             // 12,632,064 B
  unsigned short* h1p  = (unsigned short*)(ws + 12632064);  // 12,632,064 B
  unsigned short* Wt1  = (unsigned short*)(ws + 25264128);  // 884,736 B
  unsigned short* Wt2  = (unsigned short*)(ws + 26148864);  // 884,736 B
  int*            idxv = (int*)(ws + 27033600);             // 524,288 B

  prep_all<<<dim3(PB_TOT), dim3(256), 0, stream>>>(
      w1, w2, Wt1, Wt2, h1p, target, idxv, (const float4*)x, xp);
  conv_fused<0><<<dim3(640), dim3(512), 0, stream>>>(
      xp, Wt1, b1, g1, be1, nullptr, nullptr, h1p, nullptr,
      (const float4*)x, idxv, (float4*)out, 0);
  conv_fused<1><<<dim3(640), dim3(512), 0, stream>>>(
      h1p, Wt2, b2, g2, be2, lw, lb, nullptr, dur,
      (const float4*)x, idxv, (float4*)out, 1);
}

// Round 4
// 321.384 us; speedup vs baseline: 1.7265x; 1.7265x over previous
//
#include <hip/hip_runtime.h>
#include <cstdint>
#include <cstddef>

#define B_   32
#define TIN  512
#define D_   384
#define F_   384
#define TOUT 4096
#define TPAD 514            // 512 + zero row on each side

typedef __bf16 bf16x8 __attribute__((ext_vector_type(8)));
typedef float  f32x4  __attribute__((ext_vector_type(4)));
typedef unsigned short u16x8 __attribute__((ext_vector_type(8)));

__device__ __forceinline__ unsigned short f2bf(float f) {
  unsigned int u = __float_as_uint(f);
  u += 0x7fff + ((u >> 16) & 1);   // round-to-nearest-even
  return (unsigned short)(u >> 16);
}

__device__ __forceinline__ void load16_to_lds(const void* g, void* l) {
  __builtin_amdgcn_global_load_lds(
      (const __attribute__((address_space(1))) unsigned int*)g,
      (__attribute__((address_space(3))) unsigned int*)l, 16, 0, 0);
}

// ---------------------------------------------------------------- prep (fused)
// [0,32)      cumsum+searchsorted -> idxv
// [32,+1152)  weight transpose: thread e reads w[e*3..+2], writes Wt[k][e]
// [.., +96)   zero h1p pad rows
// [.., +3084) pad+convert x -> xp (8 bf16 per thread)
#define PB_CUM 32
#define PB_W   1152
#define PB_Z   96
#define PB_PX  3084
#define PB_TOT (PB_CUM + PB_W + PB_Z + PB_PX)

__global__ __launch_bounds__(256) void prep_all(
    const float* __restrict__ w1, const float* __restrict__ w2,
    unsigned short* __restrict__ Wt1, unsigned short* __restrict__ Wt2,
    unsigned short* __restrict__ h1p,
    const int* __restrict__ target, int* __restrict__ idxv,
    const float4* __restrict__ x4, unsigned short* __restrict__ xp) {
  int bx = blockIdx.x;
  int tid = threadIdx.x;

  if (bx < PB_CUM) {
    __shared__ int ends[512];
    __shared__ int ps[256];
    int b = bx;
    int a0 = target[b * TIN + 2 * tid];
    int a1 = target[b * TIN + 2 * tid + 1];
    ps[tid] = a0 + a1;
    __syncthreads();
    for (int off = 1; off < 256; off <<= 1) {
      int add = (tid >= off) ? ps[tid - off] : 0;
      __syncthreads();
      ps[tid] += add;
      __syncthreads();
    }
    int incl = ps[tid];
    ends[2 * tid + 1] = incl;
    ends[2 * tid]     = incl - a1;
    __syncthreads();
    for (int p = 0; p < 16; ++p) {
      int m = p * 256 + tid;
      int lo = 0, hi = 512;              // first j with ends[j] > m
      while (lo < hi) {
        int mid = (lo + hi) >> 1;
        if (ends[mid] <= m) lo = mid + 1; else hi = mid;
      }
      idxv[b * TOUT + m] = (lo < TIN) ? lo : -1;
    }
    return;
  }
  bx -= PB_CUM;

  if (bx < PB_W) {
    int g = bx * 256 + tid;                     // < 294912
    const int FD = F_ * D_;                     // 147456
    int which = g >= FD;
    const float* w = which ? w2 : w1;
    unsigned short* o = which ? Wt2 : Wt1;
    int e = g - which * FD;                     // f*D_+d
    o[e]          = f2bf(w[e * 3 + 0]);
    o[FD + e]     = f2bf(w[e * 3 + 1]);
    o[2 * FD + e] = f2bf(w[e * 3 + 2]);
    return;
  }
  bx -= PB_W;

  if (bx < PB_Z) {
    int z = bx * 256 + tid;                     // < 24576
    int zr = z / D_;
    int c = z - zr * D_;
    int b = zr >> 1;
    int tp = (zr & 1) ? (TPAD - 1) : 0;
    h1p[((size_t)(b * TPAD + tp)) * D_ + c] = 0;
    return;
  }
  bx -= PB_Z;

  {
    int g = bx * 256 + tid;                     // 32*514*48 = 789,504
    int row = g / 48;
    int c8 = g - row * 48;
    int b = row / TPAD;
    int tp = row - b * TPAD;
    u16x8 o;
    if (tp == 0 || tp == TPAD - 1) {
      o = (u16x8)0;
    } else {
      float4 v0 = x4[((size_t)(b * TIN + tp - 1)) * 96 + c8 * 2];
      float4 v1 = x4[((size_t)(b * TIN + tp - 1)) * 96 + c8 * 2 + 1];
      o[0] = f2bf(v0.x); o[1] = f2bf(v0.y); o[2] = f2bf(v0.z); o[3] = f2bf(v0.w);
      o[4] = f2bf(v1.x); o[5] = f2bf(v1.y); o[6] = f2bf(v1.z); o[7] = f2bf(v1.w);
    }
    *(u16x8*)(xp + (size_t)row * D_ + c8 * 8) = o;
  }
}

// ---------------------------------------------------------------- conv+LN+gather
// Grid 768 x 512thr. bx%3==0 -> conv tile (256: 64 rows x all 384 cols,
// K=1152); else gather slice (512 per launch). Conv: 8 waves side by side,
// each 64x48 = 4x3 mfma_f32_16x16x32_bf16 -> acc 48 VGPR/thread (no spill).
// Epilogue: 16-row LDS groups (24 KB aliases staging), LN per row; MODE 0:
// relu->bf16 h1p, MODE 1: dot(lin_w)+bias->dur.
template <int MODE>
__global__ __launch_bounds__(512, 1) void conv_fused(
    const unsigned short* __restrict__ Ap, const unsigned short* __restrict__ Wt,
    const float* __restrict__ bias,
    const float* __restrict__ gam, const float* __restrict__ bet,
    const float* __restrict__ lw, const float* __restrict__ lb,
    unsigned short* __restrict__ hp, float* __restrict__ dur,
    const float4* __restrict__ x4, const int* __restrict__ idxv,
    float4* __restrict__ out4, int half) {
  __shared__ __align__(16) char smem[28672];
  unsigned short* As = (unsigned short*)smem;            // 4 KB  (64x32 bf16)
  unsigned short* Bs = (unsigned short*)(smem + 4096);   // 24 KB (384x32 bf16)
  float* epi = (float*)smem;                             // 24 KB (16x384 f32)

  const int bx  = blockIdx.x;
  const int tid = threadIdx.x;
  const int cbq = bx / 3;

  if (bx - cbq * 3 != 0) {
    // ---------------- gather: 512 blocks x 24 rounds x 512 float4
    int gidx = bx - cbq - 1;                    // 0..511
    size_t g = (size_t)half * 6291456 + (size_t)gidx * 512 + tid;
    for (int it = 0; it < 24; ++it, g += 262144) {
      unsigned int gu = (unsigned int)g;
      int fr = gu / 96;
      int c  = gu - fr * 96;
      int id = idxv[fr];
      int b  = fr >> 12;
      float4 v = {0.f, 0.f, 0.f, 0.f};
      if (id >= 0) v = x4[(size_t)(b * TIN + id) * 96 + c];
      out4[g] = v;
    }
    return;
  }

  // ---------------- conv tile: rows m0..m0+63, cols 0..383
  const int wave = tid >> 6;        // 0..7
  const int lane = tid & 63;
  const int quad = lane >> 4;
  const int l15  = lane & 15;
  const int wn = wave * 48;
  const int m0 = cbq * 64;
  const int b  = m0 >> 9;           // 64-row tiles never cross batch
  const int t0 = m0 & 511;
  const int arow = tid >> 2;        // 0..127
  const int acol = (tid & 3) * 8;   // 0,8,16,24

  f32x4 acc[4][3];
  for (int i = 0; i < 4; ++i)
    for (int j = 0; j < 3; ++j)
      acc[i][j] = (f32x4){0.f, 0.f, 0.f, 0.f};

  for (int kc = 0; kc < 36; ++kc) {
    int kw = kc / 12;
    int d0 = (kc - kw * 12) * 32;
    if (tid < 256)   // waves 0..3 stage A (64 rows x 32 cols)
      load16_to_lds(Ap + (size_t)(b * TPAD + t0 + arow + kw) * D_ + d0 + acol,
                    (char*)As + wave * 1024);
    for (int r = 0; r < 3; ++r)     // all 8 waves stage B (384 x 32)
      load16_to_lds(Wt + (size_t)(kw * F_ + r * 128 + arow) * D_ + d0 + acol,
                    (char*)Bs + r * 8192 + wave * 1024);
    __syncthreads();   // drains vmcnt -> tiles visible
    bf16x8 av[4], bv[3];
    for (int mi = 0; mi < 4; ++mi)
      av[mi] = *(const bf16x8*)(As + (mi * 16 + l15) * 32 + quad * 8);
    for (int ni = 0; ni < 3; ++ni)
      bv[ni] = *(const bf16x8*)(Bs + (wn + ni * 16 + l15) * 32 + quad * 8);
    for (int mi = 0; mi < 4; ++mi)
      for (int ni = 0; ni < 3; ++ni)
        acc[mi][ni] = __builtin_amdgcn_mfma_f32_16x16x32_bf16(av[mi], bv[ni], acc[mi][ni], 0, 0, 0);
    __syncthreads();   // protect LDS from next staging
  }

  // per-lane column params for LN (cols lane + j*64)
  float gv[6], bv2[6], lwv[6];
  for (int j = 0; j < 6; ++j) {
    int c = lane + j * 64;
    gv[j]  = gam[c];
    bv2[j] = bet[c];
    if (MODE == 1) lwv[j] = lw[c];
  }
  float bb[3];
  for (int ni = 0; ni < 3; ++ni) bb[ni] = bias[wn + ni * 16 + l15];

  for (int g4 = 0; g4 < 4; ++g4) {            // 16-row groups = acc[g4]
    __syncthreads();
    for (int ni = 0; ni < 3; ++ni) {
      int c = wn + ni * 16 + l15;
      for (int r = 0; r < 4; ++r)             // C/D: row = quad*4 + r
        epi[(quad * 4 + r) * 384 + c] = acc[g4][ni][r] + bb[ni];
    }
    __syncthreads();
    for (int rr = 0; rr < 2; ++rr) {          // 16 rows / 8 waves
      int lr = wave * 2 + rr;
      int grow = m0 + g4 * 16 + lr;           // global row = b*512 + t
      const float* p = epi + lr * 384;
      float v[6], s = 0.f, ss = 0.f;
      for (int j = 0; j < 6; ++j) {
        v[j] = p[lane + j * 64];
        s += v[j];
        ss += v[j] * v[j];
      }
      for (int off = 32; off; off >>= 1) {
        s  += __shfl_xor(s, off);
        ss += __shfl_xor(ss, off);
      }
      float mean = s * (1.f / 384.f);
      float var  = ss * (1.f / 384.f) - mean * mean;
      float rstd = rsqrtf(var + 1e-5f);
      if (MODE == 0) {
        unsigned short* o = hp + ((size_t)(b * TPAD + (grow & 511) + 1)) * D_;
        for (int j = 0; j < 6; ++j) {
          float y = (v[j] - mean) * rstd * gv[j] + bv2[j];
          y = y > 0.f ? y : 0.f;
          o[lane + j * 64] = f2bf(y);
        }
      } else {
        float a = 0.f;
        for (int j = 0; j < 6; ++j) {
          float y = (v[j] - mean) * rstd * gv[j] + bv2[j];
          y = y > 0.f ? y : 0.f;
          a += y * lwv[j];
        }
        for (int off = 32; off; off >>= 1) a += __shfl_xor(a, off);
        if (lane == 0) dur[grow] = a + lb[0];
      }
    }
  }
}

// ---------------------------------------------------------------- launch
extern "C" void kernel_launch(void* const* d_in, const int* in_sizes, int n_in,
                              void* d_out, int out_size, void* d_ws, size_t ws_size,
                              hipStream_t stream) {
  const float* x      = (const float*)d_in[0];
  const int*   target = (const int*)d_in[1];
  const float* w1  = (const float*)d_in[3];
  const float* b1  = (const float*)d_in[4];
  const float* g1  = (const float*)d_in[5];
  const float* be1 = (const float*)d_in[6];
  const float* w2  = (const float*)d_in[7];
  const float* b2  = (const float*)d_in[8];
  const float* g2  = (const float*)d_in[9];
  const float* be2 = (const float*)d_in[10];
  const float* lw  = (const float*)d_in[11];
  const float* lb  = (const float*)d_in[12];

  float* out = (float*)d_out;
  float* dur = out + (size_t)B_ * TOUT * D_;   // outputs concatenated flat

  char* ws = (char*)d_ws;
  unsigned short* xp   = (unsigned short*)(ws);             // 12,632,064 B
  unsigned short* h1p  = (unsigned short*)(ws + 12632064);  // 12,632,064 B
  unsigned short* Wt1  = (unsigned short*)(ws + 25264128);  // 884,736 B
  unsigned short* Wt2  = (unsigned short*)(ws + 26148864);  // 884,736 B
  int*            idxv = (int*)(ws + 27033600);             // 524,288 B

  prep_all<<<dim3(PB_TOT), dim3(256), 0, stream>>>(
      w1, w2, Wt1, Wt2, h1p, target, idxv, (const float4*)x, xp);
  conv_fused<0><<<dim3(768), dim3(512), 0, stream>>>(
      xp, Wt1, b1, g1, be1, nullptr, nullptr, h1p, nullptr,
      (const float4*)x, idxv, (float4*)out, 0);
  conv_fused<1><<<dim3(768), dim3(512), 0, stream>>>(
      h1p, Wt2, b2, g2, be2, lw, lb, nullptr, dur,
      (const float4*)x, idxv, (float4*)out, 1);
}